// Round 1
// baseline (88.001 us; speedup 1.0000x reference)
//
#include <hip/hip_runtime.h>
#include <math.h>

#define NC     10
#define NM     128
#define NGEN   4
#define NDEPTH 9
#define NPT    1023
#define NTREES 1024
#define NLEAF  512
#define BSTRIDE 11   // pad 10 -> 11 floats: gcd(11,32)=1, avoids 8-way LDS bank conflict

__global__ __launch_bounds__(256)
void htmm_up(const int* __restrict__ x,
             const float* __restrict__ A,
             const float* __restrict__ B,
             const float* __restrict__ Pi,
             float* __restrict__ out)
{
    __shared__ float sA[NC][NC];        // smA[i][j] for this g
    __shared__ float sB[NC][NM];        // smB[c][m] for this g
    __shared__ float sPi[NC];
    __shared__ float buf0[NLEAF][BSTRIDE];     // 22528 B
    __shared__ float buf1[NLEAF/2][BSTRIDE];   // 11264 B
    __shared__ float warpsum[4];

    const int bid  = blockIdx.x;
    const int tree = bid >> 2;
    const int g    = bid & 3;
    const int tid  = threadIdx.x;

    // ---- load raw B[:, :, g] into LDS (coalesced-ish; tiny) ----
    for (int idx = tid; idx < NC * NM; idx += 256) {
        const int c = idx >> 7, m = idx & 127;
        sB[c][m] = B[(c * NM + m) * NGEN + g];
    }
    __syncthreads();

    // ---- softmax B over m (axis=1): 10 rows, one thread each ----
    if (tid < NC) {
        const int c = tid;
        float mx = -1e30f;
        for (int m = 0; m < NM; ++m) mx = fmaxf(mx, sB[c][m]);
        float s = 0.f;
        for (int m = 0; m < NM; ++m) { float e = __expf(sB[c][m] - mx); sB[c][m] = e; s += e; }
        const float rs = 1.f / s;
        for (int m = 0; m < NM; ++m) sB[c][m] *= rs;
    }
    // ---- softmax A over i (axis=0) for each column j ----
    if (tid >= 32 && tid < 32 + NC) {
        const int j = tid - 32;
        float col[NC];
        float mx = -1e30f;
        #pragma unroll
        for (int i = 0; i < NC; ++i) { col[i] = A[(i * NC + j) * NGEN + g]; mx = fmaxf(mx, col[i]); }
        float s = 0.f;
        #pragma unroll
        for (int i = 0; i < NC; ++i) { col[i] = __expf(col[i] - mx); s += col[i]; }
        const float rs = 1.f / s;
        #pragma unroll
        for (int i = 0; i < NC; ++i) sA[i][j] = col[i] * rs;
    }
    // ---- softmax Pi over c ----
    if (tid == 64) {
        float col[NC];
        float mx = -1e30f;
        #pragma unroll
        for (int i = 0; i < NC; ++i) { col[i] = Pi[i * NGEN + g]; mx = fmaxf(mx, col[i]); }
        float s = 0.f;
        #pragma unroll
        for (int i = 0; i < NC; ++i) { col[i] = __expf(col[i] - mx); s += col[i]; }
        const float rs = 1.f / s;
        #pragma unroll
        for (int i = 0; i < NC; ++i) sPi[i] = col[i] * rs;
    }
    __syncthreads();

    float llacc = 0.f;
    const int base = tree * NPT;

    // ---- leaf level: within-tree nodes 511..1022, local l in [0,512) ----
    for (int l = tid; l < NLEAF; l += 256) {
        const int xv = x[base + 511 + l];
        float b[NC];
        float nu = 0.f;
        #pragma unroll
        for (int i = 0; i < NC; ++i) { b[i] = sPi[i] * sB[i][xv]; nu += b[i]; }
        const float rnu = 1.f / nu;
        #pragma unroll
        for (int i = 0; i < NC; ++i) buf0[l][i] = b[i] * rnu;
        llacc += __logf(nu);
    }
    __syncthreads();

    // ---- internal levels k = 8 .. 0 (ping-pong level buffers) ----
    float* bc = &buf0[0][0];   // children buffer (level k+1)
    float* bp = &buf1[0][0];   // parent buffer (level k)
    for (int k = NDEPTH - 1; k >= 0; --k) {
        const int n = 1 << k;
        const int lvlbase = base + n - 1;   // within-tree first node at depth k is 2^k-1
        for (int l = tid; l < n; l += 256) {
            const float* c0 = bc + (2 * l) * BSTRIDE;
            const float* c1 = bc + (2 * l + 1) * BSTRIDE;
            float t[NC];
            #pragma unroll
            for (int i = 0; i < NC; ++i) t[i] = 0.f;
            #pragma unroll
            for (int j = 0; j < NC; ++j) {
                const float bj = c0[j] + c1[j];   // sA[i][j] is wave-uniform -> broadcast
                #pragma unroll
                for (int i = 0; i < NC; ++i) t[i] += sA[i][j] * bj;
            }
            const int xv = x[lvlbase + l];
            float nu = 0.f;
            #pragma unroll
            for (int i = 0; i < NC; ++i) { t[i] = t[i] * 0.5f * sB[i][xv]; nu += t[i]; }
            const float rnu = 1.f / nu;
            float* p = bp + l * BSTRIDE;
            #pragma unroll
            for (int i = 0; i < NC; ++i) p[i] = t[i] * rnu;
            llacc += __logf(nu);
        }
        __syncthreads();
        float* tmp = bc; bc = bp; bp = tmp;
    }

    // ---- block-reduce llacc (wave shuffle + 4 partials) ----
    #pragma unroll
    for (int off = 32; off > 0; off >>= 1) llacc += __shfl_down(llacc, off);
    if ((tid & 63) == 0) warpsum[tid >> 6] = llacc;
    __syncthreads();
    if (tid == 0) out[tree * NGEN + g] = warpsum[0] + warpsum[1] + warpsum[2] + warpsum[3];
}

extern "C" void kernel_launch(void* const* d_in, const int* in_sizes, int n_in,
                              void* d_out, int out_size, void* d_ws, size_t ws_size,
                              hipStream_t stream) {
    const int*   x  = (const int*)d_in[0];
    const float* A  = (const float*)d_in[1];
    const float* B  = (const float*)d_in[2];
    const float* Pi = (const float*)d_in[3];
    float* out = (float*)d_out;
    htmm_up<<<NTREES * NGEN, 256, 0, stream>>>(x, A, B, Pi, out);
}

// Round 2
// 68.557 us; speedup vs baseline: 1.2836x; 1.2836x over previous
//
#include <hip/hip_runtime.h>
#include <math.h>

#define NC     10
#define NM     128
#define NGEN   4
#define NPT    1023
#define NTREES 1024
#define ST     11   // pad 10 -> 11 floats: gcd(11,32)=1 keeps stride-ST access ~2-way

__global__ __launch_bounds__(256)
void htmm_up(const int* __restrict__ x,
             const float* __restrict__ A,
             const float* __restrict__ B,
             const float* __restrict__ Pi,
             float* __restrict__ out)
{
    __shared__ float sA[NC][NC];       // smA[i][j]
    __shared__ float sB[NC][NM];       // smB[c][m]
    __shared__ float sPi[NC];
    __shared__ float bufA[256][ST];    // level-8 out; reused for level-4
    __shared__ float bufB[64][ST];     // level-6 out; reused for level-2
    __shared__ float warpsum[4];

    const int bid  = blockIdx.x;
    const int tree = bid >> 2;
    const int g    = bid & 3;
    const int tid  = threadIdx.x;
    const int wave = tid >> 6, lane = tid & 63;

    // ---- wave-parallel softmax of B rows (axis=1 over M) ----
    for (int c = wave; c < NC; c += 4) {
        float v0 = B[(c * NM + lane) * NGEN + g];
        float v1 = B[(c * NM + lane + 64) * NGEN + g];
        float mx = fmaxf(v0, v1);
        #pragma unroll
        for (int off = 32; off; off >>= 1) mx = fmaxf(mx, __shfl_xor(mx, off));
        float e0 = __expf(v0 - mx), e1 = __expf(v1 - mx);
        float s = e0 + e1;
        #pragma unroll
        for (int off = 32; off; off >>= 1) s += __shfl_xor(s, off);
        float rs = 1.f / s;
        sB[c][lane] = e0 * rs;
        sB[c][lane + 64] = e1 * rs;
    }
    // ---- A column softmax (axis=0 over i), thread j<10 ----
    if (tid < NC) {
        const int j = tid;
        float col[NC], mx = -1e30f;
        #pragma unroll
        for (int i = 0; i < NC; ++i) { col[i] = A[(i * NC + j) * NGEN + g]; mx = fmaxf(mx, col[i]); }
        float s = 0.f;
        #pragma unroll
        for (int i = 0; i < NC; ++i) { col[i] = __expf(col[i] - mx); s += col[i]; }
        const float rs = 1.f / s;
        #pragma unroll
        for (int i = 0; i < NC; ++i) sA[i][j] = col[i] * rs;
    }
    // ---- Pi softmax ----
    if (tid == 16) {
        float col[NC], mx = -1e30f;
        #pragma unroll
        for (int i = 0; i < NC; ++i) { col[i] = Pi[i * NGEN + g]; mx = fmaxf(mx, col[i]); }
        float s = 0.f;
        #pragma unroll
        for (int i = 0; i < NC; ++i) { col[i] = __expf(col[i] - mx); s += col[i]; }
        const float rs = 1.f / s;
        #pragma unroll
        for (int i = 0; i < NC; ++i) sPi[i] = col[i] * rs;
    }
    __syncthreads();

    const int base = tree * NPT;
    float llacc;

    // ---- stage 1: fused leaves + level-8 parents. thread l owns parent 255+l ----
    {
        const int l = tid;
        const int xv0 = x[base + 511 + 2 * l];
        const int xv1 = x[base + 512 + 2 * l];
        const int xvp = x[base + 255 + l];
        float b0[NC], b1[NC];
        float nu0 = 0.f, nu1 = 0.f;
        #pragma unroll
        for (int i = 0; i < NC; ++i) {
            b0[i] = sPi[i] * sB[i][xv0]; nu0 += b0[i];
            b1[i] = sPi[i] * sB[i][xv1]; nu1 += b1[i];
        }
        llacc = __logf(nu0) + __logf(nu1);
        const float r0 = 1.f / nu0, r1 = 1.f / nu1;
        float tp[NC];
        #pragma unroll
        for (int i = 0; i < NC; ++i) tp[i] = 0.f;
        #pragma unroll
        for (int j = 0; j < NC; ++j) {
            const float bj = b0[j] * r0 + b1[j] * r1;
            #pragma unroll
            for (int i = 0; i < NC; ++i) tp[i] += sA[i][j] * bj;
        }
        float nup = 0.f;
        #pragma unroll
        for (int i = 0; i < NC; ++i) { tp[i] *= 0.5f * sB[i][xvp]; nup += tp[i]; }
        llacc += __logf(nup);
        const float rp = 1.f / nup;
        #pragma unroll
        for (int i = 0; i < NC; ++i) bufA[l][i] = tp[i] * rp;
    }
    __syncthreads();

    // ---- stages 2..5: fused level pairs (7+6),(5+4),(3+2),(1+0) ----
    float* gin  = &bufA[0][0];
    float* gout = &bufB[0][0];
    int cs = 127, n = 64;     // child-level start, parent count
    for (int stage = 0; stage < 4; ++stage) {
        if (tid < n) {
            const int l = tid;
            const float* g0 = gin + (4 * l + 0) * ST;
            const float* g1 = gin + (4 * l + 1) * ST;
            const float* g2 = gin + (4 * l + 2) * ST;
            const float* g3 = gin + (4 * l + 3) * ST;
            float s0[NC], s1[NC];
            #pragma unroll
            for (int j = 0; j < NC; ++j) { s0[j] = g0[j] + g1[j]; s1[j] = g2[j] + g3[j]; }
            float t0[NC], t1[NC];
            #pragma unroll
            for (int i = 0; i < NC; ++i) { t0[i] = 0.f; t1[i] = 0.f; }
            #pragma unroll
            for (int j = 0; j < NC; ++j) {
                #pragma unroll
                for (int i = 0; i < NC; ++i) {
                    const float av = sA[i][j];
                    t0[i] += av * s0[j];
                    t1[i] += av * s1[j];
                }
            }
            const int xc0 = x[base + cs + 2 * l];
            const int xc1 = x[base + cs + 1 + 2 * l];
            const int xp  = x[base + (cs >> 1) + l];
            float nu0 = 0.f, nu1 = 0.f;
            #pragma unroll
            for (int i = 0; i < NC; ++i) {
                t0[i] *= 0.5f * sB[i][xc0]; nu0 += t0[i];
                t1[i] *= 0.5f * sB[i][xc1]; nu1 += t1[i];
            }
            llacc += __logf(nu0) + __logf(nu1);
            const float r0 = 1.f / nu0, r1 = 1.f / nu1;
            float tp[NC];
            #pragma unroll
            for (int i = 0; i < NC; ++i) tp[i] = 0.f;
            #pragma unroll
            for (int j = 0; j < NC; ++j) {
                const float bj = t0[j] * r0 + t1[j] * r1;
                #pragma unroll
                for (int i = 0; i < NC; ++i) tp[i] += sA[i][j] * bj;
            }
            float nup = 0.f;
            #pragma unroll
            for (int i = 0; i < NC; ++i) { tp[i] *= 0.5f * sB[i][xp]; nup += tp[i]; }
            llacc += __logf(nup);
            const float rp = 1.f / nup;
            float* o = gout + l * ST;
            #pragma unroll
            for (int i = 0; i < NC; ++i) o[i] = tp[i] * rp;
        }
        __syncthreads();
        float* tmp = gin; gin = gout; gout = tmp;
        cs >>= 2; n >>= 2;    // 127->31->7->1 ; 64->16->4->1
    }

    // ---- block-reduce llacc ----
    #pragma unroll
    for (int off = 32; off > 0; off >>= 1) llacc += __shfl_down(llacc, off);
    if ((tid & 63) == 0) warpsum[tid >> 6] = llacc;
    __syncthreads();
    if (tid == 0) out[tree * NGEN + g] = warpsum[0] + warpsum[1] + warpsum[2] + warpsum[3];
}

extern "C" void kernel_launch(void* const* d_in, const int* in_sizes, int n_in,
                              void* d_out, int out_size, void* d_ws, size_t ws_size,
                              hipStream_t stream) {
    const int*   x  = (const int*)d_in[0];
    const float* A  = (const float*)d_in[1];
    const float* B  = (const float*)d_in[2];
    const float* Pi = (const float*)d_in[3];
    float* out = (float*)d_out;
    htmm_up<<<NTREES * NGEN, 256, 0, stream>>>(x, A, B, Pi, out);
}

// Round 3
// 58.642 us; speedup vs baseline: 1.5006x; 1.1691x over previous
//
#include <hip/hip_runtime.h>
#include <math.h>

#define NC     10
#define NM     128
#define NGEN   4
#define NPT    1023
#define NTREES 1024
#define ST     11   // pad 10 -> 11 floats: gcd(11,32)=1 keeps stride-ST access ~2-way
#define K2U    16   // (tree,g) units per block in the top kernel

// ---------------- shared device helpers ----------------

__device__ __forceinline__ void softmax_setup(const float* __restrict__ A,
                                              const float* __restrict__ B,
                                              const float* __restrict__ Pi,
                                              int g, int tid,
                                              float (*sA)[NC], float (*sB)[NM], float* sPi,
                                              bool needPi)
{
    const int wave = tid >> 6, lane = tid & 63;
    // wave-parallel softmax of B rows (axis=1 over M)
    for (int c = wave; c < NC; c += 4) {
        float v0 = B[(c * NM + lane) * NGEN + g];
        float v1 = B[(c * NM + lane + 64) * NGEN + g];
        float mx = fmaxf(v0, v1);
        #pragma unroll
        for (int off = 32; off; off >>= 1) mx = fmaxf(mx, __shfl_xor(mx, off));
        float e0 = __expf(v0 - mx), e1 = __expf(v1 - mx);
        float s = e0 + e1;
        #pragma unroll
        for (int off = 32; off; off >>= 1) s += __shfl_xor(s, off);
        float rs = 1.f / s;
        sB[c][lane] = e0 * rs;
        sB[c][lane + 64] = e1 * rs;
    }
    // A column softmax (axis=0 over i)
    if (tid < NC) {
        const int j = tid;
        float col[NC], mx = -1e30f;
        #pragma unroll
        for (int i = 0; i < NC; ++i) { col[i] = A[(i * NC + j) * NGEN + g]; mx = fmaxf(mx, col[i]); }
        float s = 0.f;
        #pragma unroll
        for (int i = 0; i < NC; ++i) { col[i] = __expf(col[i] - mx); s += col[i]; }
        const float rs = 1.f / s;
        #pragma unroll
        for (int i = 0; i < NC; ++i) sA[i][j] = col[i] * rs;
    }
    if (needPi && tid == 16) {
        float col[NC], mx = -1e30f;
        #pragma unroll
        for (int i = 0; i < NC; ++i) { col[i] = Pi[i * NGEN + g]; mx = fmaxf(mx, col[i]); }
        float s = 0.f;
        #pragma unroll
        for (int i = 0; i < NC; ++i) { col[i] = __expf(col[i] - mx); s += col[i]; }
        const float rs = 1.f / s;
        #pragma unroll
        for (int i = 0; i < NC; ++i) sPi[i] = col[i] * rs;
    }
}

// fused 2-level step: 4 grandchild betas -> 2 child nodes -> 1 parent node.
// gc0..gc3: grandchild beta pointers (stride-1, NC floats each)
// xc0,xc1,xp: observation values for the two children and the parent
// po: output beta (NC floats), returns sum of 3 logs.
__device__ __forceinline__ float fused_pair(const float (*sA)[NC], const float (*sB)[NM],
                                            const float* gc0, const float* gc1,
                                            const float* gc2, const float* gc3,
                                            int xc0, int xc1, int xp, float* po)
{
    float s0[NC], s1[NC];
    #pragma unroll
    for (int j = 0; j < NC; ++j) { s0[j] = gc0[j] + gc1[j]; s1[j] = gc2[j] + gc3[j]; }
    float t0[NC], t1[NC];
    #pragma unroll
    for (int i = 0; i < NC; ++i) { t0[i] = 0.f; t1[i] = 0.f; }
    #pragma unroll
    for (int j = 0; j < NC; ++j) {
        #pragma unroll
        for (int i = 0; i < NC; ++i) {
            const float av = sA[i][j];
            t0[i] += av * s0[j];
            t1[i] += av * s1[j];
        }
    }
    float nu0 = 0.f, nu1 = 0.f;
    #pragma unroll
    for (int i = 0; i < NC; ++i) {
        t0[i] *= 0.5f * sB[i][xc0]; nu0 += t0[i];
        t1[i] *= 0.5f * sB[i][xc1]; nu1 += t1[i];
    }
    float ll = __logf(nu0) + __logf(nu1);
    const float r0 = 1.f / nu0, r1 = 1.f / nu1;
    float tp[NC];
    #pragma unroll
    for (int i = 0; i < NC; ++i) tp[i] = 0.f;
    #pragma unroll
    for (int j = 0; j < NC; ++j) {
        const float bj = t0[j] * r0 + t1[j] * r1;
        #pragma unroll
        for (int i = 0; i < NC; ++i) tp[i] += sA[i][j] * bj;
    }
    float nup = 0.f;
    #pragma unroll
    for (int i = 0; i < NC; ++i) { tp[i] *= 0.5f * sB[i][xp]; nup += tp[i]; }
    ll += __logf(nup);
    const float rp = 1.f / nup;
    #pragma unroll
    for (int i = 0; i < NC; ++i) po[i] = tp[i] * rp;
    return ll;
}

// ---------------- kernel 1: leaves + levels 8..6 ----------------
// writes beta6[U][64][10] and ll1[U], U = g*NTREES + tree

__global__ __launch_bounds__(256)
void htmm_bottom(const int* __restrict__ x,
                 const float* __restrict__ A,
                 const float* __restrict__ B,
                 const float* __restrict__ Pi,
                 float* __restrict__ beta6,
                 float* __restrict__ ll1)
{
    __shared__ float sA[NC][NC];
    __shared__ float sB[NC][NM];
    __shared__ float sPi[NC];
    __shared__ float bufA[256][ST];
    __shared__ float bufB[64][ST];
    __shared__ float warpsum[4];

    const int bid  = blockIdx.x;
    const int tree = bid >> 2;
    const int g    = bid & 3;
    const int tid  = threadIdx.x;

    softmax_setup(A, B, Pi, g, tid, sA, sB, sPi, true);
    __syncthreads();

    const int base = tree * NPT;
    float llacc;

    // stage 1: fused leaves + level-8 parents. thread l owns parent 255+l
    {
        const int l = tid;
        const int xv0 = x[base + 511 + 2 * l];
        const int xv1 = x[base + 512 + 2 * l];
        const int xvp = x[base + 255 + l];
        float b0[NC], b1[NC];
        float nu0 = 0.f, nu1 = 0.f;
        #pragma unroll
        for (int i = 0; i < NC; ++i) {
            b0[i] = sPi[i] * sB[i][xv0]; nu0 += b0[i];
            b1[i] = sPi[i] * sB[i][xv1]; nu1 += b1[i];
        }
        llacc = __logf(nu0) + __logf(nu1);
        const float r0 = 1.f / nu0, r1 = 1.f / nu1;
        float tp[NC];
        #pragma unroll
        for (int i = 0; i < NC; ++i) tp[i] = 0.f;
        #pragma unroll
        for (int j = 0; j < NC; ++j) {
            const float bj = b0[j] * r0 + b1[j] * r1;
            #pragma unroll
            for (int i = 0; i < NC; ++i) tp[i] += sA[i][j] * bj;
        }
        float nup = 0.f;
        #pragma unroll
        for (int i = 0; i < NC; ++i) { tp[i] *= 0.5f * sB[i][xvp]; nup += tp[i]; }
        llacc += __logf(nup);
        const float rp = 1.f / nup;
        #pragma unroll
        for (int i = 0; i < NC; ++i) bufA[l][i] = tp[i] * rp;
    }
    __syncthreads();

    // stage 2: fused levels 7+6 (64 parents at L6)
    if (tid < 64) {
        const int l = tid;
        float po[NC];
        llacc += fused_pair(sA, sB,
                            &bufA[4 * l][0], &bufA[4 * l + 1][0],
                            &bufA[4 * l + 2][0], &bufA[4 * l + 3][0],
                            x[base + 127 + 2 * l], x[base + 128 + 2 * l], x[base + 63 + l],
                            po);
        #pragma unroll
        for (int i = 0; i < NC; ++i) bufB[l][i] = po[i];
    }
    __syncthreads();

    // write level-6 betas (64 x 10) coalesced
    const int U = g * NTREES + tree;
    float* bout = beta6 + (size_t)U * 640;
    for (int idx = tid; idx < 640; idx += 256) bout[idx] = bufB[idx / 10][idx % 10];

    // block-reduce llacc
    #pragma unroll
    for (int off = 32; off > 0; off >>= 1) llacc += __shfl_down(llacc, off);
    if ((tid & 63) == 0) warpsum[tid >> 6] = llacc;
    __syncthreads();
    if (tid == 0) ll1[U] = warpsum[0] + warpsum[1] + warpsum[2] + warpsum[3];
}

// ---------------- kernel 2: levels 5..0 for K2U units per block ----------------

__global__ __launch_bounds__(256)
void htmm_top(const int* __restrict__ x,
              const float* __restrict__ A,
              const float* __restrict__ B,
              const float* __restrict__ beta6,
              const float* __restrict__ ll1,
              float* __restrict__ out)
{
    __shared__ float sA[NC][NC];
    __shared__ float sB[NC][NM];
    __shared__ float cb[K2U][64][ST];   // level-6 children
    __shared__ float pb[K2U][16][ST];   // level-4 out
    __shared__ float pb2[K2U][4][ST];   // level-2 out
    __shared__ float sll[K2U];

    const int b        = blockIdx.x;
    const int g        = b >> 6;
    const int treeBase = (b & 63) * K2U;
    const int tid      = threadIdx.x;

    softmax_setup(A, B, (const float*)nullptr, g, tid, sA, sB, (float*)nullptr, false);

    const int Ubase = g * NTREES + treeBase;
    for (int idx = tid; idx < K2U * 640; idx += 256) {
        const int u = idx / 640, r = idx % 640;
        cb[u][r / 10][r % 10] = beta6[(size_t)(Ubase + u) * 640 + r];
    }
    if (tid < K2U) sll[tid] = 0.f;
    __syncthreads();

    // Stage A: levels 5+4. 16 units x 16 parents = 256 threads
    {
        const int u = tid >> 4, l = tid & 15;
        const int tb = (treeBase + u) * NPT;
        float po[NC];
        float lla = fused_pair(sA, sB,
                               &cb[u][4 * l][0], &cb[u][4 * l + 1][0],
                               &cb[u][4 * l + 2][0], &cb[u][4 * l + 3][0],
                               x[tb + 31 + 2 * l], x[tb + 32 + 2 * l], x[tb + 15 + l],
                               po);
        #pragma unroll
        for (int i = 0; i < NC; ++i) pb[u][l][i] = po[i];
        // reduce within 16-lane unit groups
        #pragma unroll
        for (int off = 8; off; off >>= 1) lla += __shfl_down(lla, off);
        if ((tid & 15) == 0) sll[u] += lla;
    }
    __syncthreads();

    // Stage B: levels 3+2. 16 units x 4 parents = 64 threads
    if (tid < 64) {
        const int u = tid >> 2, l = tid & 3;
        const int tb = (treeBase + u) * NPT;
        float po[NC];
        float llb = fused_pair(sA, sB,
                               &pb[u][4 * l][0], &pb[u][4 * l + 1][0],
                               &pb[u][4 * l + 2][0], &pb[u][4 * l + 3][0],
                               x[tb + 7 + 2 * l], x[tb + 8 + 2 * l], x[tb + 3 + l],
                               po);
        #pragma unroll
        for (int i = 0; i < NC; ++i) pb2[u][l][i] = po[i];
        #pragma unroll
        for (int off = 2; off; off >>= 1) llb += __shfl_down(llb, off);
        if ((tid & 3) == 0) sll[u] += llb;
    }
    __syncthreads();

    // Stage C: levels 1+0. 16 units x 1 = 16 threads
    if (tid < K2U) {
        const int u = tid;
        const int tb = (treeBase + u) * NPT;
        float po[NC];
        float llc = fused_pair(sA, sB,
                               &pb2[u][0][0], &pb2[u][1][0],
                               &pb2[u][2][0], &pb2[u][3][0],
                               x[tb + 1], x[tb + 2], x[tb + 0],
                               po);
        sll[u] += llc;
    }
    __syncthreads();

    if (tid < K2U)
        out[(size_t)(treeBase + tid) * NGEN + g] = sll[tid] + ll1[Ubase + tid];
}

// ---------------- fallback: monolithic (known-good R2 kernel) ----------------

__global__ __launch_bounds__(256)
void htmm_mono(const int* __restrict__ x,
               const float* __restrict__ A,
               const float* __restrict__ B,
               const float* __restrict__ Pi,
               float* __restrict__ out)
{
    __shared__ float sA[NC][NC];
    __shared__ float sB[NC][NM];
    __shared__ float sPi[NC];
    __shared__ float bufA[256][ST];
    __shared__ float bufB[64][ST];
    __shared__ float warpsum[4];

    const int bid  = blockIdx.x;
    const int tree = bid >> 2;
    const int g    = bid & 3;
    const int tid  = threadIdx.x;

    softmax_setup(A, B, Pi, g, tid, sA, sB, sPi, true);
    __syncthreads();

    const int base = tree * NPT;
    float llacc;
    {
        const int l = tid;
        const int xv0 = x[base + 511 + 2 * l];
        const int xv1 = x[base + 512 + 2 * l];
        const int xvp = x[base + 255 + l];
        float b0[NC], b1[NC];
        float nu0 = 0.f, nu1 = 0.f;
        #pragma unroll
        for (int i = 0; i < NC; ++i) {
            b0[i] = sPi[i] * sB[i][xv0]; nu0 += b0[i];
            b1[i] = sPi[i] * sB[i][xv1]; nu1 += b1[i];
        }
        llacc = __logf(nu0) + __logf(nu1);
        const float r0 = 1.f / nu0, r1 = 1.f / nu1;
        float tp[NC];
        #pragma unroll
        for (int i = 0; i < NC; ++i) tp[i] = 0.f;
        #pragma unroll
        for (int j = 0; j < NC; ++j) {
            const float bj = b0[j] * r0 + b1[j] * r1;
            #pragma unroll
            for (int i = 0; i < NC; ++i) tp[i] += sA[i][j] * bj;
        }
        float nup = 0.f;
        #pragma unroll
        for (int i = 0; i < NC; ++i) { tp[i] *= 0.5f * sB[i][xvp]; nup += tp[i]; }
        llacc += __logf(nup);
        const float rp = 1.f / nup;
        #pragma unroll
        for (int i = 0; i < NC; ++i) bufA[l][i] = tp[i] * rp;
    }
    __syncthreads();

    float* gin  = &bufA[0][0];
    float* gout = &bufB[0][0];
    int cs = 127, n = 64;
    for (int stage = 0; stage < 4; ++stage) {
        if (tid < n) {
            const int l = tid;
            float po[NC];
            llacc += fused_pair(sA, sB,
                                gin + (4 * l) * ST, gin + (4 * l + 1) * ST,
                                gin + (4 * l + 2) * ST, gin + (4 * l + 3) * ST,
                                x[base + cs + 2 * l], x[base + cs + 1 + 2 * l],
                                x[base + (cs >> 1) + l], po);
            float* o = gout + l * ST;
            #pragma unroll
            for (int i = 0; i < NC; ++i) o[i] = po[i];
        }
        __syncthreads();
        float* tmp = gin; gin = gout; gout = tmp;
        cs >>= 2; n >>= 2;
    }

    #pragma unroll
    for (int off = 32; off > 0; off >>= 1) llacc += __shfl_down(llacc, off);
    if ((tid & 63) == 0) warpsum[tid >> 6] = llacc;
    __syncthreads();
    if (tid == 0) out[tree * NGEN + g] = warpsum[0] + warpsum[1] + warpsum[2] + warpsum[3];
}

extern "C" void kernel_launch(void* const* d_in, const int* in_sizes, int n_in,
                              void* d_out, int out_size, void* d_ws, size_t ws_size,
                              hipStream_t stream) {
    const int*   x  = (const int*)d_in[0];
    const float* A  = (const float*)d_in[1];
    const float* B  = (const float*)d_in[2];
    const float* Pi = (const float*)d_in[3];
    float* out = (float*)d_out;

    const size_t need = (size_t)NTREES * NGEN * 640 * 4 + (size_t)NTREES * NGEN * 4;
    if (ws_size >= need) {
        float* beta6 = (float*)d_ws;
        float* ll1   = beta6 + (size_t)NTREES * NGEN * 640;
        htmm_bottom<<<NTREES * NGEN, 256, 0, stream>>>(x, A, B, Pi, beta6, ll1);
        htmm_top<<<256, 256, 0, stream>>>(x, A, B, beta6, ll1, out);
    } else {
        htmm_mono<<<NTREES * NGEN, 256, 0, stream>>>(x, A, B, Pi, out);
    }
}

// Round 4
// 56.127 us; speedup vs baseline: 1.5679x; 1.0448x over previous
//
#include <hip/hip_runtime.h>
#include <math.h>

#define NC     10
#define NCP    12     // padded state stride (floats); 48B rows, 16B-aligned, 8 start-banks
#define NM     128
#define NGEN   4
#define NPT    1023
#define NTREES 1024
#define K2U    16

#define RCPF(x) __builtin_amdgcn_rcpf(x)

struct F12 { float4 a, b, c; };

__device__ __forceinline__ F12 ld12(const float* p) {
    F12 r; const float4* q = (const float4*)p;
    r.a = q[0]; r.b = q[1]; r.c = q[2]; return r;
}
__device__ __forceinline__ void fma10(float* t, const F12& c, float s) {
    t[0] += c.a.x * s; t[1] += c.a.y * s; t[2] += c.a.z * s; t[3] += c.a.w * s;
    t[4] += c.b.x * s; t[5] += c.b.y * s; t[6] += c.b.z * s; t[7] += c.b.w * s;
    t[8] += c.c.x * s; t[9] += c.c.y * s;
}
__device__ __forceinline__ void mul10(float* t, const F12& r) {
    t[0] *= r.a.x; t[1] *= r.a.y; t[2] *= r.a.z; t[3] *= r.a.w;
    t[4] *= r.b.x; t[5] *= r.b.y; t[6] *= r.b.z; t[7] *= r.b.w;
    t[8] *= r.c.x; t[9] *= r.c.y;
}
__device__ __forceinline__ void mulset10(float* t, const F12& p, const F12& r) {
    t[0] = p.a.x * r.a.x; t[1] = p.a.y * r.a.y; t[2] = p.a.z * r.a.z; t[3] = p.a.w * r.a.w;
    t[4] = p.b.x * r.b.x; t[5] = p.b.y * r.b.y; t[6] = p.b.z * r.b.z; t[7] = p.b.w * r.b.w;
    t[8] = p.c.x * r.c.x; t[9] = p.c.y * r.c.y;
}
__device__ __forceinline__ float sum10(const float* v) {
    return (((v[0] + v[1]) + (v[2] + v[3])) + ((v[4] + v[5]) + (v[6] + v[7]))) + (v[8] + v[9]);
}

// softmaxes into transposed/padded LDS layouts. sACol[j][i] = 0.5*smA[i][j].
__device__ __forceinline__ void setup_params(const float* __restrict__ A,
                                             const float* __restrict__ B,
                                             const float* __restrict__ Pi,
                                             int g, int tid,
                                             float (*sACol)[NCP], float (*sBT)[NCP],
                                             float* sPiP, bool needPi)
{
    const int wave = tid >> 6, lane = tid & 63;
    const int nw = blockDim.x >> 6;
    for (int c = wave; c < NC; c += nw) {
        float v0 = B[(c * NM + lane) * NGEN + g];
        float v1 = B[(c * NM + lane + 64) * NGEN + g];
        float mx = fmaxf(v0, v1);
        #pragma unroll
        for (int off = 32; off; off >>= 1) mx = fmaxf(mx, __shfl_xor(mx, off));
        float e0 = __expf(v0 - mx), e1 = __expf(v1 - mx);
        float s = e0 + e1;
        #pragma unroll
        for (int off = 32; off; off >>= 1) s += __shfl_xor(s, off);
        float rs = 1.f / s;
        sBT[lane][c]      = e0 * rs;
        sBT[lane + 64][c] = e1 * rs;
    }
    if (tid < NC) {        // column j softmax over i, store col-major with 0.5 folded
        const int j = tid;
        float col[NC], mx = -1e30f;
        #pragma unroll
        for (int i = 0; i < NC; ++i) { col[i] = A[(i * NC + j) * NGEN + g]; mx = fmaxf(mx, col[i]); }
        float s = 0.f;
        #pragma unroll
        for (int i = 0; i < NC; ++i) { col[i] = __expf(col[i] - mx); s += col[i]; }
        const float rs = 0.5f / s;
        #pragma unroll
        for (int i = 0; i < NC; ++i) sACol[j][i] = col[i] * rs;
        sACol[j][10] = 0.f; sACol[j][11] = 0.f;
    }
    if (needPi && tid == 16) {
        float col[NC], mx = -1e30f;
        #pragma unroll
        for (int i = 0; i < NC; ++i) { col[i] = Pi[i * NGEN + g]; mx = fmaxf(mx, col[i]); }
        float s = 0.f;
        #pragma unroll
        for (int i = 0; i < NC; ++i) { col[i] = __expf(col[i] - mx); s += col[i]; }
        const float rs = 1.f / s;
        #pragma unroll
        for (int i = 0; i < NC; ++i) sPiP[i] = col[i] * rs;
        sPiP[10] = 0.f; sPiP[11] = 0.f;
    }
}

// fused 2-level step, SoA buffers: bin[j*SIN + node], bout[j*SOUT + l].
// grandchildren = bin columns 4l..4l+3; returns ll of 2 children + parent.
template<int SIN, int SOUT>
__device__ __forceinline__ float fused_step(const float (*sACol)[NCP], const float (*sBT)[NCP],
                                            const float* bin, float* bout, int l,
                                            int xc0, int xc1, int xp)
{
    float t0[NC], t1[NC];
    #pragma unroll
    for (int i = 0; i < NC; ++i) { t0[i] = 0.f; t1[i] = 0.f; }
    #pragma unroll
    for (int j = 0; j < NC; ++j) {
        float4 gv = *(const float4*)(bin + j * SIN + 4 * l);
        F12 col = ld12(&sACol[j][0]);
        fma10(t0, col, gv.x + gv.y);
        fma10(t1, col, gv.z + gv.w);
    }
    mul10(t0, ld12(&sBT[xc0][0]));
    mul10(t1, ld12(&sBT[xc1][0]));
    const float nu0 = sum10(t0), nu1 = sum10(t1);
    const float r0 = RCPF(nu0),  r1 = RCPF(nu1);
    float ll = __logf(nu0) + __logf(nu1);

    float tp[NC];
    #pragma unroll
    for (int i = 0; i < NC; ++i) tp[i] = 0.f;
    #pragma unroll
    for (int j = 0; j < NC; ++j)
        fma10(tp, ld12(&sACol[j][0]), t0[j] * r0 + t1[j] * r1);
    mul10(tp, ld12(&sBT[xp][0]));
    const float nup = sum10(tp);
    ll += __logf(nup);
    const float rp = RCPF(nup);
    #pragma unroll
    for (int j = 0; j < NC; ++j) bout[j * SOUT + l] = tp[j] * rp;
    return ll;
}

// leaves (2) + level-8 parent; writes SoA bout[j*SOUT + l].
template<int SOUT>
__device__ __forceinline__ float leaf_step(const float (*sACol)[NCP], const float (*sBT)[NCP],
                                           const float* sPiP, float* bout, int l,
                                           int xv0, int xv1, int xvp)
{
    F12 pi = ld12(sPiP);
    float b0[NC], b1[NC];
    mulset10(b0, pi, ld12(&sBT[xv0][0]));
    mulset10(b1, pi, ld12(&sBT[xv1][0]));
    const float nu0 = sum10(b0), nu1 = sum10(b1);
    const float r0 = RCPF(nu0),  r1 = RCPF(nu1);
    float ll = __logf(nu0) + __logf(nu1);

    float tp[NC];
    #pragma unroll
    for (int i = 0; i < NC; ++i) tp[i] = 0.f;
    #pragma unroll
    for (int j = 0; j < NC; ++j)
        fma10(tp, ld12(&sACol[j][0]), b0[j] * r0 + b1[j] * r1);
    mul10(tp, ld12(&sBT[xvp][0]));
    const float nup = sum10(tp);
    ll += __logf(nup);
    const float rp = RCPF(nup);
    #pragma unroll
    for (int j = 0; j < NC; ++j) bout[j * SOUT + l] = tp[j] * rp;
    return ll;
}

// ---------------- kernel 1: leaves + levels 8..6 ----------------
__global__ __launch_bounds__(256)
void htmm_bottom(const int* __restrict__ x,
                 const float* __restrict__ A,
                 const float* __restrict__ B,
                 const float* __restrict__ Pi,
                 float* __restrict__ beta6,
                 float* __restrict__ ll1)
{
    __shared__ __align__(16) float sACol[NC][NCP];
    __shared__ __align__(16) float sBT[NM][NCP];
    __shared__ __align__(16) float sPiP[NCP];
    __shared__ __align__(16) float bA[NC][256];   // L8 betas, SoA
    __shared__ __align__(16) float bB[NC][64];    // L6 betas, SoA
    __shared__ float warpsum[4];

    const int bid = blockIdx.x, tree = bid >> 2, g = bid & 3, tid = threadIdx.x;
    setup_params(A, B, Pi, g, tid, sACol, sBT, sPiP, true);
    __syncthreads();

    const int base = tree * NPT;
    float llacc = leaf_step<256>(sACol, sBT, sPiP, &bA[0][0], tid,
                                 x[base + 511 + 2 * tid], x[base + 512 + 2 * tid],
                                 x[base + 255 + tid]);
    __syncthreads();

    if (tid < 64)
        llacc += fused_step<256, 64>(sACol, sBT, &bA[0][0], &bB[0][0], tid,
                                     x[base + 127 + 2 * tid], x[base + 128 + 2 * tid],
                                     x[base + 63 + tid]);
    __syncthreads();

    const int U = g * NTREES + tree;
    float* bout = beta6 + (size_t)U * 640;
    for (int idx = tid; idx < 640; idx += 256) bout[idx] = bB[idx >> 6][idx & 63];

    #pragma unroll
    for (int off = 32; off > 0; off >>= 1) llacc += __shfl_down(llacc, off);
    if ((tid & 63) == 0) warpsum[tid >> 6] = llacc;
    __syncthreads();
    if (tid == 0) ll1[U] = warpsum[0] + warpsum[1] + warpsum[2] + warpsum[3];
}

// ---------------- kernel 2: levels 5..0, K2U units per block ----------------
__global__ __launch_bounds__(256)
void htmm_top(const int* __restrict__ x,
              const float* __restrict__ A,
              const float* __restrict__ B,
              const float* __restrict__ beta6,
              const float* __restrict__ ll1,
              float* __restrict__ out)
{
    __shared__ __align__(16) float sACol[NC][NCP];
    __shared__ __align__(16) float sBT[NM][NCP];
    __shared__ __align__(16) float cb[K2U][NC][64];   // L6 betas
    __shared__ __align__(16) float pb[K2U][NC][20];   // L4 betas
    __shared__ __align__(16) float pb2[K2U][NC][4];   // L2 betas
    __shared__ float sll[K2U];

    const int b = blockIdx.x, g = b >> 6, treeBase = (b & 63) * K2U, tid = threadIdx.x;
    setup_params(A, B, (const float*)nullptr, g, tid, sACol, sBT, (float*)nullptr, false);

    const int Ubase = g * NTREES + treeBase;
    for (int idx = tid; idx < K2U * 640; idx += 256) {
        const int u = idx / 640, r = idx % 640;
        cb[u][r >> 6][r & 63] = beta6[(size_t)(Ubase + u) * 640 + r];
    }
    if (tid < K2U) sll[tid] = 0.f;
    __syncthreads();

    // Stage A: levels 5+4 — 16 units x 16 parents = 256 threads
    {
        const int u = tid >> 4, l = tid & 15;
        const int tb = (treeBase + u) * NPT;
        float lla = fused_step<64, 20>(sACol, sBT, &cb[u][0][0], &pb[u][0][0], l,
                                       x[tb + 31 + 2 * l], x[tb + 32 + 2 * l], x[tb + 15 + l]);
        #pragma unroll
        for (int off = 8; off; off >>= 1) lla += __shfl_down(lla, off);
        if (l == 0) sll[u] += lla;
    }
    __syncthreads();

    // Stage B: levels 3+2 — 16 units x 4 parents
    if (tid < 64) {
        const int u = tid >> 2, l = tid & 3;
        const int tb = (treeBase + u) * NPT;
        float llb = fused_step<20, 4>(sACol, sBT, &pb[u][0][0], &pb2[u][0][0], l,
                                      x[tb + 7 + 2 * l], x[tb + 8 + 2 * l], x[tb + 3 + l]);
        #pragma unroll
        for (int off = 2; off; off >>= 1) llb += __shfl_down(llb, off);
        if (l == 0) sll[u] += llb;
    }
    __syncthreads();

    // Stage C: levels 1+0 — 16 units x 1
    if (tid < K2U) {
        const int u = tid;
        const int tb = (treeBase + u) * NPT;
        sll[u] += fused_step<4, 1>(sACol, sBT, &pb2[u][0][0], &pb[u][0][0] /*scratch*/, 0,
                                   x[tb + 1], x[tb + 2], x[tb + 0]);
    }
    __syncthreads();

    if (tid < K2U)
        out[(size_t)(treeBase + tid) * NGEN + g] = sll[tid] + ll1[Ubase + tid];
}

// ---------------- fallback: monolithic, same building blocks ----------------
__global__ __launch_bounds__(256)
void htmm_mono(const int* __restrict__ x,
               const float* __restrict__ A,
               const float* __restrict__ B,
               const float* __restrict__ Pi,
               float* __restrict__ out)
{
    __shared__ __align__(16) float sACol[NC][NCP];
    __shared__ __align__(16) float sBT[NM][NCP];
    __shared__ __align__(16) float sPiP[NCP];
    __shared__ __align__(16) float bA[NC][256];
    __shared__ __align__(16) float bB[NC][64];
    __shared__ __align__(16) float bC[NC][20];
    __shared__ __align__(16) float bD[NC][4];
    __shared__ float warpsum[4];

    const int bid = blockIdx.x, tree = bid >> 2, g = bid & 3, tid = threadIdx.x;
    setup_params(A, B, Pi, g, tid, sACol, sBT, sPiP, true);
    __syncthreads();

    const int base = tree * NPT;
    float llacc = leaf_step<256>(sACol, sBT, sPiP, &bA[0][0], tid,
                                 x[base + 511 + 2 * tid], x[base + 512 + 2 * tid],
                                 x[base + 255 + tid]);
    __syncthreads();
    if (tid < 64)
        llacc += fused_step<256, 64>(sACol, sBT, &bA[0][0], &bB[0][0], tid,
                                     x[base + 127 + 2 * tid], x[base + 128 + 2 * tid],
                                     x[base + 63 + tid]);
    __syncthreads();
    if (tid < 16)
        llacc += fused_step<64, 20>(sACol, sBT, &bB[0][0], &bC[0][0], tid,
                                    x[base + 31 + 2 * tid], x[base + 32 + 2 * tid],
                                    x[base + 15 + tid]);
    __syncthreads();
    if (tid < 4)
        llacc += fused_step<20, 4>(sACol, sBT, &bC[0][0], &bD[0][0], tid,
                                   x[base + 7 + 2 * tid], x[base + 8 + 2 * tid],
                                   x[base + 3 + tid]);
    __syncthreads();
    if (tid == 0)
        llacc += fused_step<4, 1>(sACol, sBT, &bD[0][0], &bC[0][0] /*scratch*/, 0,
                                  x[base + 1], x[base + 2], x[base + 0]);

    #pragma unroll
    for (int off = 32; off > 0; off >>= 1) llacc += __shfl_down(llacc, off);
    if ((tid & 63) == 0) warpsum[tid >> 6] = llacc;
    __syncthreads();
    if (tid == 0) out[tree * NGEN + g] = warpsum[0] + warpsum[1] + warpsum[2] + warpsum[3];
}

extern "C" void kernel_launch(void* const* d_in, const int* in_sizes, int n_in,
                              void* d_out, int out_size, void* d_ws, size_t ws_size,
                              hipStream_t stream) {
    const int*   x  = (const int*)d_in[0];
    const float* A  = (const float*)d_in[1];
    const float* B  = (const float*)d_in[2];
    const float* Pi = (const float*)d_in[3];
    float* out = (float*)d_out;

    const size_t need = (size_t)NTREES * NGEN * 640 * 4 + (size_t)NTREES * NGEN * 4;
    if (ws_size >= need) {
        float* beta6 = (float*)d_ws;
        float* ll1   = beta6 + (size_t)NTREES * NGEN * 640;
        htmm_bottom<<<NTREES * NGEN, 256, 0, stream>>>(x, A, B, Pi, beta6, ll1);
        htmm_top<<<256, 256, 0, stream>>>(x, A, B, beta6, ll1, out);
    } else {
        htmm_mono<<<NTREES * NGEN, 256, 0, stream>>>(x, A, B, Pi, out);
    }
}

// Round 5
// 33.983 us; speedup vs baseline: 2.5896x; 1.6517x over previous
//
#include <hip/hip_runtime.h>
#include <math.h>

#define NC     10
#define NCP    12     // padded state stride (floats); 48B rows, 16B aligned
#define NM     128
#define NGEN   4
#define NPT    1023
#define NTREES 1024

#define RCPF(x) __builtin_amdgcn_rcpf(x)

struct F12 { float4 a, b, c; };

__device__ __forceinline__ F12 ld12(const float* p) {
    F12 r; const float4* q = (const float4*)p;
    r.a = q[0]; r.b = q[1]; r.c = q[2]; return r;
}
__device__ __forceinline__ void unpack10(float* t, const F12& r) {
    t[0] = r.a.x; t[1] = r.a.y; t[2] = r.a.z; t[3] = r.a.w;
    t[4] = r.b.x; t[5] = r.b.y; t[6] = r.b.z; t[7] = r.b.w;
    t[8] = r.c.x; t[9] = r.c.y;
}
__device__ __forceinline__ void fma10(float* t, const F12& c, float s) {
    t[0] += c.a.x * s; t[1] += c.a.y * s; t[2] += c.a.z * s; t[3] += c.a.w * s;
    t[4] += c.b.x * s; t[5] += c.b.y * s; t[6] += c.b.z * s; t[7] += c.b.w * s;
    t[8] += c.c.x * s; t[9] += c.c.y * s;
}
__device__ __forceinline__ void mul10(float* t, const F12& r) {
    t[0] *= r.a.x; t[1] *= r.a.y; t[2] *= r.a.z; t[3] *= r.a.w;
    t[4] *= r.b.x; t[5] *= r.b.y; t[6] *= r.b.z; t[7] *= r.b.w;
    t[8] *= r.c.x; t[9] *= r.c.y;
}
__device__ __forceinline__ float sum10(const float* v) {
    return (((v[0] + v[1]) + (v[2] + v[3])) + ((v[4] + v[5]) + (v[6] + v[7]))) + (v[8] + v[9]);
}

// two leaves -> normalized-pair-sum sc[j]; returns log nu0 + log nu1
__device__ __forceinline__ float leaf_pair(const float (*sBTpi)[NCP], int xv0, int xv1, float* sc) {
    float b0[NC], b1[NC];
    unpack10(b0, ld12(&sBTpi[xv0][0]));
    unpack10(b1, ld12(&sBTpi[xv1][0]));
    const float nu0 = sum10(b0), nu1 = sum10(b1);
    const float r0 = RCPF(nu0), r1 = RCPF(nu1);
    #pragma unroll
    for (int j = 0; j < NC; ++j) sc[j] = b0[j] * r0 + b1[j] * r1;
    return __logf(nu0) + __logf(nu1);
}

// fused 2-level step on SoA LDS buffers: bin[j*SIN + node], bout[j*SOUT + l].
template<int SIN, int SOUT>
__device__ __forceinline__ float fused_step(const float (*sACol)[NCP], const float (*sBT)[NCP],
                                            const float* bin, float* bout, int l,
                                            int xc0, int xc1, int xp)
{
    float t0[NC], t1[NC];
    #pragma unroll
    for (int i = 0; i < NC; ++i) { t0[i] = 0.f; t1[i] = 0.f; }
    #pragma unroll
    for (int j = 0; j < NC; ++j) {
        float4 gv = *(const float4*)(bin + j * SIN + 4 * l);
        F12 col = ld12(&sACol[j][0]);
        fma10(t0, col, gv.x + gv.y);
        fma10(t1, col, gv.z + gv.w);
    }
    mul10(t0, ld12(&sBT[xc0][0]));
    mul10(t1, ld12(&sBT[xc1][0]));
    const float nu0 = sum10(t0), nu1 = sum10(t1);
    const float r0 = RCPF(nu0), r1 = RCPF(nu1);
    float ll = __logf(nu0) + __logf(nu1);

    float tp[NC];
    #pragma unroll
    for (int i = 0; i < NC; ++i) tp[i] = 0.f;
    #pragma unroll
    for (int j = 0; j < NC; ++j)
        fma10(tp, ld12(&sACol[j][0]), t0[j] * r0 + t1[j] * r1);
    mul10(tp, ld12(&sBT[xp][0]));
    const float nup = sum10(tp);
    ll += __logf(nup);
    const float rp = RCPF(nup);
    #pragma unroll
    for (int j = 0; j < NC; ++j) bout[j * SOUT + l] = tp[j] * rp;
    return ll;
}

// ---------------- single fused kernel ----------------
// block = 256 threads = 4 (tree,g) units; wave u handles tree treeBase+u, one g per block.
// Each lane owns one L6 subtree (8 leaves + 4 L8 + 2 L7 + 1 L6) fully in registers.
__global__ __launch_bounds__(256)
void htmm_fused(const int* __restrict__ x,
                const float* __restrict__ A,
                const float* __restrict__ B,
                const float* __restrict__ Pi,
                float* __restrict__ out)
{
    __shared__ __align__(16) float sACol[NC][NCP];   // 0.5*smA[i][j], col-major
    __shared__ __align__(16) float sBT[NM][NCP];     // smB^T rows
    __shared__ __align__(16) float sBTpi[NM][NCP];   // pi ⊙ smB^T rows (for leaves)
    __shared__ __align__(16) float sPiP[NCP];
    __shared__ __align__(16) float sB6[4][NC][64];   // L6 betas per unit, SoA
    __shared__ __align__(16) float pb[4][NC][20];    // L4 betas (+ scratch)
    __shared__ __align__(16) float pb2[4][NC][4];    // L2 betas

    const int bid = blockIdx.x;
    const int g = bid >> 8;
    const int treeBase = (bid & 255) * 4;
    const int tid = threadIdx.x;
    const int u = tid >> 6, lane = tid & 63;

    // ---- parameter softmaxes ----
    {
        // B rows: wave-parallel softmax over M
        for (int c = u; c < NC; c += 4) {
            float v0 = B[(c * NM + lane) * NGEN + g];
            float v1 = B[(c * NM + lane + 64) * NGEN + g];
            float mx = fmaxf(v0, v1);
            #pragma unroll
            for (int off = 32; off; off >>= 1) mx = fmaxf(mx, __shfl_xor(mx, off));
            float e0 = __expf(v0 - mx), e1 = __expf(v1 - mx);
            float s = e0 + e1;
            #pragma unroll
            for (int off = 32; off; off >>= 1) s += __shfl_xor(s, off);
            float rs = 1.f / s;
            sBT[lane][c]      = e0 * rs;
            sBT[lane + 64][c] = e1 * rs;
        }
        if (tid < NC) {   // A column softmax, 0.5 folded, stored col-major
            const int j = tid;
            float col[NC], mx = -1e30f;
            #pragma unroll
            for (int i = 0; i < NC; ++i) { col[i] = A[(i * NC + j) * NGEN + g]; mx = fmaxf(mx, col[i]); }
            float s = 0.f;
            #pragma unroll
            for (int i = 0; i < NC; ++i) { col[i] = __expf(col[i] - mx); s += col[i]; }
            const float rs = 0.5f / s;
            #pragma unroll
            for (int i = 0; i < NC; ++i) sACol[j][i] = col[i] * rs;
            sACol[j][10] = 0.f; sACol[j][11] = 0.f;
        }
        if (tid == 16) {  // Pi softmax
            float col[NC], mx = -1e30f;
            #pragma unroll
            for (int i = 0; i < NC; ++i) { col[i] = Pi[i * NGEN + g]; mx = fmaxf(mx, col[i]); }
            float s = 0.f;
            #pragma unroll
            for (int i = 0; i < NC; ++i) { col[i] = __expf(col[i] - mx); s += col[i]; }
            const float rs = 1.f / s;
            #pragma unroll
            for (int i = 0; i < NC; ++i) sPiP[i] = col[i] * rs;
            sPiP[10] = 0.f; sPiP[11] = 0.f;
        }
    }
    __syncthreads();
    if (tid < NM) {   // sBTpi[m][c] = pi[c] * sBT[m][c]
        F12 pi = ld12(sPiP);
        F12 r  = ld12(&sBT[tid][0]);
        sBTpi[tid][0] = pi.a.x * r.a.x; sBTpi[tid][1] = pi.a.y * r.a.y;
        sBTpi[tid][2] = pi.a.z * r.a.z; sBTpi[tid][3] = pi.a.w * r.a.w;
        sBTpi[tid][4] = pi.b.x * r.b.x; sBTpi[tid][5] = pi.b.y * r.b.y;
        sBTpi[tid][6] = pi.b.z * r.b.z; sBTpi[tid][7] = pi.b.w * r.b.w;
        sBTpi[tid][8] = pi.c.x * r.c.x; sBTpi[tid][9] = pi.c.y * r.c.y;
    }
    __syncthreads();

    const int tree = treeBase + u;
    const int tb = tree * NPT;
    const int s = lane;

    // ---- gather observation indices early (15 loads in flight) ----
    int xl[8];
    #pragma unroll
    for (int k = 0; k < 8; ++k) xl[k] = x[tb + 511 + 8 * s + k];
    int x8[4];
    #pragma unroll
    for (int c = 0; c < 4; ++c) x8[c] = x[tb + 255 + 4 * s + c];
    const int x7a = x[tb + 127 + 2 * s];
    const int x7b = x[tb + 128 + 2 * s];
    const int x6v = x[tb + 63 + s];

    float llacc = 0.f;

    // ---- leaves -> 4 pair-sum vectors ----
    float sc[4][NC];
    #pragma unroll
    for (int c = 0; c < 4; ++c) llacc += leaf_pair(sBTpi, xl[2 * c], xl[2 * c + 1], sc[c]);

    // ---- L8: ONE A-pass, 4 accumulators ----
    float t8[4][NC];
    #pragma unroll
    for (int c = 0; c < 4; ++c)
        #pragma unroll
        for (int i = 0; i < NC; ++i) t8[c][i] = 0.f;
    #pragma unroll
    for (int j = 0; j < NC; ++j) {
        F12 col = ld12(&sACol[j][0]);
        #pragma unroll
        for (int c = 0; c < 4; ++c) fma10(t8[c], col, sc[c][j]);
    }
    #pragma unroll
    for (int c = 0; c < 4; ++c) {   // finish L8 nodes; store normalized betas back into sc
        mul10(t8[c], ld12(&sBT[x8[c]][0]));
        const float nu = sum10(t8[c]);
        llacc += __logf(nu);
        const float r = RCPF(nu);
        #pragma unroll
        for (int j = 0; j < NC; ++j) sc[c][j] = t8[c][j] * r;
    }

    // ---- L7: one A-pass, 2 accumulators ----
    float s70[NC], s71[NC];
    #pragma unroll
    for (int j = 0; j < NC; ++j) { s70[j] = sc[0][j] + sc[1][j]; s71[j] = sc[2][j] + sc[3][j]; }
    float t70[NC], t71[NC];
    #pragma unroll
    for (int i = 0; i < NC; ++i) { t70[i] = 0.f; t71[i] = 0.f; }
    #pragma unroll
    for (int j = 0; j < NC; ++j) {
        F12 col = ld12(&sACol[j][0]);
        fma10(t70, col, s70[j]);
        fma10(t71, col, s71[j]);
    }
    mul10(t70, ld12(&sBT[x7a][0]));
    mul10(t71, ld12(&sBT[x7b][0]));
    const float nu70 = sum10(t70), nu71 = sum10(t71);
    llacc += __logf(nu70) + __logf(nu71);
    const float r70 = RCPF(nu70), r71 = RCPF(nu71);

    // ---- L6: one A-pass, 1 accumulator ----
    float tp[NC];
    #pragma unroll
    for (int i = 0; i < NC; ++i) tp[i] = 0.f;
    #pragma unroll
    for (int j = 0; j < NC; ++j)
        fma10(tp, ld12(&sACol[j][0]), t70[j] * r70 + t71[j] * r71);
    mul10(tp, ld12(&sBT[x6v][0]));
    const float nup = sum10(tp);
    llacc += __logf(nup);
    const float rp = RCPF(nup);
    #pragma unroll
    for (int j = 0; j < NC; ++j) sB6[u][j][s] = tp[j] * rp;   // SoA, lane-contiguous

    __syncthreads();

    // ---- tail: levels 5..0, wave-local per unit ----
    float lla = 0.f;
    if (lane < 16)
        lla = fused_step<64, 20>(sACol, sBT, &sB6[u][0][0], &pb[u][0][0], lane,
                                 x[tb + 31 + 2 * lane], x[tb + 32 + 2 * lane], x[tb + 15 + lane]);
    llacc += lla;
    __syncthreads();

    float llb = 0.f;
    if (lane < 4)
        llb = fused_step<20, 4>(sACol, sBT, &pb[u][0][0], &pb2[u][0][0], lane,
                                x[tb + 7 + 2 * lane], x[tb + 8 + 2 * lane], x[tb + 3 + lane]);
    llacc += llb;
    __syncthreads();

    if (lane == 0)
        llacc += fused_step<4, 1>(sACol, sBT, &pb2[u][0][0], &pb[u][0][0] /*scratch*/, 0,
                                  x[tb + 1], x[tb + 2], x[tb + 0]);

    // ---- full-wave reduce; lane 0 writes the unit's output ----
    #pragma unroll
    for (int off = 32; off; off >>= 1) llacc += __shfl_down(llacc, off);
    if (lane == 0) out[tree * NGEN + g] = llacc;
}

extern "C" void kernel_launch(void* const* d_in, const int* in_sizes, int n_in,
                              void* d_out, int out_size, void* d_ws, size_t ws_size,
                              hipStream_t stream) {
    const int*   x  = (const int*)d_in[0];
    const float* A  = (const float*)d_in[1];
    const float* B  = (const float*)d_in[2];
    const float* Pi = (const float*)d_in[3];
    float* out = (float*)d_out;
    htmm_fused<<<NTREES, 256, 0, stream>>>(x, A, B, Pi, out);  // 1024 blocks = 256 tree-groups x 4 g
}

// Round 6
// 30.232 us; speedup vs baseline: 2.9109x; 1.1241x over previous
//
#include <hip/hip_runtime.h>
#include <math.h>

#define NC     10
#define NCP    12     // padded state stride (floats); 48B rows, 16B aligned
#define NM     128
#define NGEN   4
#define NPT    1023
#define NTREES 1024

#define RCPF(x) __builtin_amdgcn_rcpf(x)

struct F12 { float4 a, b, c; };

__device__ __forceinline__ F12 ld12(const float* p) {
    F12 r; const float4* q = (const float4*)p;
    r.a = q[0]; r.b = q[1]; r.c = q[2]; return r;
}
__device__ __forceinline__ void unpack10(float* t, const F12& r) {
    t[0] = r.a.x; t[1] = r.a.y; t[2] = r.a.z; t[3] = r.a.w;
    t[4] = r.b.x; t[5] = r.b.y; t[6] = r.b.z; t[7] = r.b.w;
    t[8] = r.c.x; t[9] = r.c.y;
}
__device__ __forceinline__ void fma10(float* t, const F12& c, float s) {
    t[0] += c.a.x * s; t[1] += c.a.y * s; t[2] += c.a.z * s; t[3] += c.a.w * s;
    t[4] += c.b.x * s; t[5] += c.b.y * s; t[6] += c.b.z * s; t[7] += c.b.w * s;
    t[8] += c.c.x * s; t[9] += c.c.y * s;
}
__device__ __forceinline__ void mul10(float* t, const F12& r) {
    t[0] *= r.a.x; t[1] *= r.a.y; t[2] *= r.a.z; t[3] *= r.a.w;
    t[4] *= r.b.x; t[5] *= r.b.y; t[6] *= r.b.z; t[7] *= r.b.w;
    t[8] *= r.c.x; t[9] *= r.c.y;
}
__device__ __forceinline__ float sum10(const float* v) {
    return (((v[0] + v[1]) + (v[2] + v[3])) + ((v[4] + v[5]) + (v[6] + v[7]))) + (v[8] + v[9]);
}

// two leaves -> normalized-pair-sum sc[j]; returns log nu0 + log nu1
__device__ __forceinline__ float leaf_pair(const float (*sBTpi)[NCP], int xv0, int xv1, float* sc) {
    float b0[NC], b1[NC];
    unpack10(b0, ld12(&sBTpi[xv0][0]));
    unpack10(b1, ld12(&sBTpi[xv1][0]));
    const float nu0 = sum10(b0), nu1 = sum10(b1);
    const float r0 = RCPF(nu0), r1 = RCPF(nu1);
    #pragma unroll
    for (int j = 0; j < NC; ++j) sc[j] = b0[j] * r0 + b1[j] * r1;
    return __logf(nu0) + __logf(nu1);
}

// one internal node from a pair-sum vector sc (register A): bout = normalized beta
__device__ __forceinline__ float node_step(const F12* acol, const float (*sBT)[NCP],
                                           const float* sc, int xv, float* bout) {
    float t[NC];
    #pragma unroll
    for (int i = 0; i < NC; ++i) t[i] = 0.f;
    #pragma unroll
    for (int j = 0; j < NC; ++j) fma10(t, acol[j], sc[j]);
    mul10(t, ld12(&sBT[xv][0]));
    const float nu = sum10(t);
    const float r = RCPF(nu);
    #pragma unroll
    for (int j = 0; j < NC; ++j) bout[j] = t[j] * r;
    return __logf(nu);
}

// fused 2-level step on SoA LDS buffers, A from registers.
template<int SIN, int SOUT>
__device__ __forceinline__ float fused_step_regA(const F12* acol, const float (*sBT)[NCP],
                                                 const float* bin, float* bout, int l,
                                                 int xc0, int xc1, int xp)
{
    float t0[NC], t1[NC];
    #pragma unroll
    for (int i = 0; i < NC; ++i) { t0[i] = 0.f; t1[i] = 0.f; }
    #pragma unroll
    for (int j = 0; j < NC; ++j) {
        float4 gv = *(const float4*)(bin + j * SIN + 4 * l);
        fma10(t0, acol[j], gv.x + gv.y);
        fma10(t1, acol[j], gv.z + gv.w);
    }
    mul10(t0, ld12(&sBT[xc0][0]));
    mul10(t1, ld12(&sBT[xc1][0]));
    const float nu0 = sum10(t0), nu1 = sum10(t1);
    const float r0 = RCPF(nu0), r1 = RCPF(nu1);
    float ll = __logf(nu0) + __logf(nu1);

    float tp[NC];
    #pragma unroll
    for (int i = 0; i < NC; ++i) tp[i] = 0.f;
    #pragma unroll
    for (int j = 0; j < NC; ++j)
        fma10(tp, acol[j], t0[j] * r0 + t1[j] * r1);
    mul10(tp, ld12(&sBT[xp][0]));
    const float nup = sum10(tp);
    ll += __logf(nup);
    const float rp = RCPF(nup);
    #pragma unroll
    for (int j = 0; j < NC; ++j) bout[j * SOUT + l] = tp[j] * rp;
    return ll;
}

// ---------------- single fused kernel ----------------
// block = 256 threads = 4 (tree,g) units; wave u handles tree treeBase+u.
// Each lane owns one L6 subtree (8 leaves + 4 L8 + 2 L7 + 1 L6) in registers,
// with the softmaxed A matrix held in 30 VGPRs (no per-pass LDS reads of A).
__global__ __launch_bounds__(256)
void htmm_fused(const int* __restrict__ x,
                const float* __restrict__ A,
                const float* __restrict__ B,
                const float* __restrict__ Pi,
                float* __restrict__ out)
{
    __shared__ __align__(16) float sACol[NC][NCP];   // 0.5*smA[i][j], col-major
    __shared__ __align__(16) float sBT[NM][NCP];     // smB^T rows
    __shared__ __align__(16) float sBTpi[NM][NCP];   // pi ⊙ smB^T rows (leaves)
    __shared__ __align__(16) float sPiP[NCP];
    __shared__ __align__(16) float sB6[4][NC][64];   // L6 betas per unit, SoA
    __shared__ __align__(16) float pb[4][NC][20];    // L4 betas (+ scratch)
    __shared__ __align__(16) float pb2[4][NC][4];    // L2 betas

    const int bid = blockIdx.x;
    const int g = bid >> 8;
    const int treeBase = (bid & 255) * 4;
    const int tid = threadIdx.x;
    const int u = tid >> 6, lane = tid & 63;

    // ---- parameter softmaxes ----
    {
        for (int c = u; c < NC; c += 4) {
            float v0 = B[(c * NM + lane) * NGEN + g];
            float v1 = B[(c * NM + lane + 64) * NGEN + g];
            float mx = fmaxf(v0, v1);
            #pragma unroll
            for (int off = 32; off; off >>= 1) mx = fmaxf(mx, __shfl_xor(mx, off));
            float e0 = __expf(v0 - mx), e1 = __expf(v1 - mx);
            float s = e0 + e1;
            #pragma unroll
            for (int off = 32; off; off >>= 1) s += __shfl_xor(s, off);
            float rs = 1.f / s;
            sBT[lane][c]      = e0 * rs;
            sBT[lane + 64][c] = e1 * rs;
        }
        if (tid < NC) {   // A column softmax, 0.5 folded, stored col-major
            const int j = tid;
            float col[NC], mx = -1e30f;
            #pragma unroll
            for (int i = 0; i < NC; ++i) { col[i] = A[(i * NC + j) * NGEN + g]; mx = fmaxf(mx, col[i]); }
            float s = 0.f;
            #pragma unroll
            for (int i = 0; i < NC; ++i) { col[i] = __expf(col[i] - mx); s += col[i]; }
            const float rs = 0.5f / s;
            #pragma unroll
            for (int i = 0; i < NC; ++i) sACol[j][i] = col[i] * rs;
            sACol[j][10] = 0.f; sACol[j][11] = 0.f;
        }
        if (tid == 16) {  // Pi softmax
            float col[NC], mx = -1e30f;
            #pragma unroll
            for (int i = 0; i < NC; ++i) { col[i] = Pi[i * NGEN + g]; mx = fmaxf(mx, col[i]); }
            float s = 0.f;
            #pragma unroll
            for (int i = 0; i < NC; ++i) { col[i] = __expf(col[i] - mx); s += col[i]; }
            const float rs = 1.f / s;
            #pragma unroll
            for (int i = 0; i < NC; ++i) sPiP[i] = col[i] * rs;
            sPiP[10] = 0.f; sPiP[11] = 0.f;
        }
    }
    __syncthreads();
    if (tid < NM) {   // sBTpi[m][c] = pi[c] * sBT[m][c]
        F12 pi = ld12(sPiP);
        F12 r  = ld12(&sBT[tid][0]);
        sBTpi[tid][0] = pi.a.x * r.a.x; sBTpi[tid][1] = pi.a.y * r.a.y;
        sBTpi[tid][2] = pi.a.z * r.a.z; sBTpi[tid][3] = pi.a.w * r.a.w;
        sBTpi[tid][4] = pi.b.x * r.b.x; sBTpi[tid][5] = pi.b.y * r.b.y;
        sBTpi[tid][6] = pi.b.z * r.b.z; sBTpi[tid][7] = pi.b.w * r.b.w;
        sBTpi[tid][8] = pi.c.x * r.c.x; sBTpi[tid][9] = pi.c.y * r.c.y;
    }
    __syncthreads();

    // ---- hoist A into registers (one-time LDS read; wave-uniform broadcast) ----
    F12 acol[NC];
    #pragma unroll
    for (int j = 0; j < NC; ++j) acol[j] = ld12(&sACol[j][0]);

    const int tree = treeBase + u;
    const int tb = tree * NPT;
    const int s = lane;

    // observation indices for this lane's subtree
    int xl[8];
    #pragma unroll
    for (int k = 0; k < 8; ++k) xl[k] = x[tb + 511 + 8 * s + k];
    int x8v[4];
    #pragma unroll
    for (int c = 0; c < 4; ++c) x8v[c] = x[tb + 255 + 4 * s + c];
    const int x7a = x[tb + 127 + 2 * s];
    const int x7b = x[tb + 128 + 2 * s];
    const int x6v = x[tb + 63 + s];

    float llacc = 0.f;
    float sc[NC], ba[NC], bb[NC], b7a[NC], b7b[NC];

    // left half: leaves 0-3 -> L8 nodes 0,1 -> L7 node a
    llacc += leaf_pair(sBTpi, xl[0], xl[1], sc);
    llacc += node_step(acol, sBT, sc, x8v[0], ba);
    llacc += leaf_pair(sBTpi, xl[2], xl[3], sc);
    llacc += node_step(acol, sBT, sc, x8v[1], bb);
    #pragma unroll
    for (int j = 0; j < NC; ++j) sc[j] = ba[j] + bb[j];
    llacc += node_step(acol, sBT, sc, x7a, b7a);

    // right half: leaves 4-7 -> L8 nodes 2,3 -> L7 node b
    llacc += leaf_pair(sBTpi, xl[4], xl[5], sc);
    llacc += node_step(acol, sBT, sc, x8v[2], ba);
    llacc += leaf_pair(sBTpi, xl[6], xl[7], sc);
    llacc += node_step(acol, sBT, sc, x8v[3], bb);
    #pragma unroll
    for (int j = 0; j < NC; ++j) sc[j] = ba[j] + bb[j];
    llacc += node_step(acol, sBT, sc, x7b, b7b);

    // L6 node
    #pragma unroll
    for (int j = 0; j < NC; ++j) sc[j] = b7a[j] + b7b[j];
    llacc += node_step(acol, sBT, sc, x6v, ba);
    #pragma unroll
    for (int j = 0; j < NC; ++j) sB6[u][j][s] = ba[j];   // SoA, lane-contiguous

    __syncthreads();

    // ---- tail: levels 5..0, wave-local per unit ----
    float lla = 0.f;
    if (lane < 16)
        lla = fused_step_regA<64, 20>(acol, sBT, &sB6[u][0][0], &pb[u][0][0], lane,
                                      x[tb + 31 + 2 * lane], x[tb + 32 + 2 * lane],
                                      x[tb + 15 + lane]);
    llacc += lla;
    __syncthreads();

    float llb = 0.f;
    if (lane < 4)
        llb = fused_step_regA<20, 4>(acol, sBT, &pb[u][0][0], &pb2[u][0][0], lane,
                                     x[tb + 7 + 2 * lane], x[tb + 8 + 2 * lane],
                                     x[tb + 3 + lane]);
    llacc += llb;
    __syncthreads();

    if (lane == 0)
        llacc += fused_step_regA<4, 1>(acol, sBT, &pb2[u][0][0], &pb[u][0][0] /*scratch*/, 0,
                                       x[tb + 1], x[tb + 2], x[tb + 0]);

    // ---- full-wave reduce; lane 0 writes the unit's output ----
    #pragma unroll
    for (int off = 32; off; off >>= 1) llacc += __shfl_down(llacc, off);
    if (lane == 0) out[tree * NGEN + g] = llacc;
}

extern "C" void kernel_launch(void* const* d_in, const int* in_sizes, int n_in,
                              void* d_out, int out_size, void* d_ws, size_t ws_size,
                              hipStream_t stream) {
    const int*   x  = (const int*)d_in[0];
    const float* A  = (const float*)d_in[1];
    const float* B  = (const float*)d_in[2];
    const float* Pi = (const float*)d_in[3];
    float* out = (float*)d_out;
    htmm_fused<<<NTREES, 256, 0, stream>>>(x, A, B, Pi, out);
}